// Round 2
// baseline (557.419 us; speedup 1.0000x reference)
//
#include <hip/hip_runtime.h>
#include <hip/hip_bf16.h>

#define HID   51
#define MR    208          // 204 gate rows + y row (204) padded to 13 tiles of 16
#define SEQT  999
#define CH    111          // 999 = 9 * 111
#define NCH   9
#define EPB   16           // batch elements per block -> 256 blocks, full-width lanes
#define XST   17           // x/y LDS stride (EPB+1)
#define NTH   256          // 4 waves: waves 0-2 = 3 tiles, wave 3 = tiles 9-12 + service
#define BSTR  72           // bcol row stride in halves (144 B: 16B-aligned, free 2-way)

typedef __attribute__((ext_vector_type(8))) short  short8;   // 8 bf16 = 4 VGPRs
typedef __attribute__((ext_vector_type(4))) float  floatx4;

// A_ext[208][64] bf16, row r = 4u+gate, PRE-SCALED by -log2(e) (i,f,o) or
// -2*log2(e) (g) so the MFMA output is directly an exp2 argument.
//   rows 0..203: cols 0..50 <- W_hh[gate*51+u][k], col 51 <- W_ih[gate*51+u]
//   row  204   : cols 0..50 <- W_fc[k] UNSCALED  (y_{t-1} falls out of the MFMA)
__global__ void prep_kernel(const float* __restrict__ W_hh,
                            const float* __restrict__ W_ih,
                            const float* __restrict__ W_fc,
                            __hip_bfloat16* __restrict__ A_ext)
{
    const float K1 = 1.442695040889f;
    int idx = blockIdx.x * blockDim.x + threadIdx.x;
    if (idx >= MR * 64) return;
    int r = idx >> 6, k = idx & 63;
    int u = r >> 2, gate = r & 3;
    float v = 0.f;
    if (r == 204) {
        if (k < HID) v = W_fc[k];
    } else if (u < HID) {
        float s = (gate == 2) ? (-2.f * K1) : (-K1);
        if (k < HID)      v = s * W_hh[(gate * HID + u) * HID + k];
        else if (k == 51) v = s * W_ih[gate * HID + u];
    }
    A_ext[idx] = __float2bfloat16(v);
}

__launch_bounds__(NTH)
__global__ void lstm_mfma_kernel(const float* __restrict__ x,
                                 const float* __restrict__ b_ih,
                                 const float* __restrict__ b_hh,
                                 const float* __restrict__ b_fc,
                                 const __hip_bfloat16* __restrict__ A_ext,
                                 float* __restrict__ out)
{
    __shared__ __hip_bfloat16 bcol[2][16 * BSTR];
    __shared__ float x_lds[(CH + 1) * XST];   // +1 lookahead for row-51 prewrite
    __shared__ float y_lds[CH * XST];         // slot tt holds y[t0 + tt - 1]

    const int tid  = threadIdx.x;
    const int w    = tid >> 6;    // wave 0..3
    const int lane = tid & 63;
    const int e    = lane & 15;   // MFMA col — all 16 live
    const int g4   = lane >> 4;   // lane group
    const int e0   = blockIdx.x * EPB;

    const int  NT  = (w == 3) ? 4 : 3;   // tiles this wave owns
    const int  T0  = 3 * w;              // first tile (w3: 9,10,11,12)
    const bool xsv = (w == 0) && (g4 == 0);   // x-row service on light wave 0

    const float K1  = 1.442695040889f;
    const float K2N = -2.885390081777f;      // -2*log2(e)

    short8  A0[4], A1[4];
    floatx4 bq[4];
    float   cs[4] = {0.f, 0.f, 0.f, 0.f};
    int     wr[4];                            // bcol write row per tile
    bool    real[4];                          // u < HID ?

#pragma unroll
    for (int ti = 0; ti < 4; ++ti) {
        bq[ti] = (floatx4){0.f, 0.f, 0.f, 0.f};
        wr[ti] = 63; real[ti] = false;
        if (ti < NT) {
            int T = T0 + ti;
            int m = T * 16 + e;
            A0[ti] = *(const short8*)&A_ext[m * 64 + g4 * 8];
            A1[ti] = *(const short8*)&A_ext[m * 64 + 32 + g4 * 8];
            int u = 4 * T + g4;
            if (u < HID) {
                wr[ti] = u; real[ti] = true;
#pragma unroll
                for (int gg = 0; gg < 4; ++gg) {
                    float s = (gg == 2) ? (-2.f * K1) : (-K1);
                    bq[ti][gg] = s * (b_ih[gg * HID + u] + b_hh[gg * HID + u]);
                }
            }
        }
    }
    const bool yln = (w == 3) && (g4 == 3);   // tile 12, row 204 = y row

    for (int i = tid; i < 16 * BSTR; i += NTH) {
        bcol[0][i] = __float2bfloat16(0.f);
        bcol[1][i] = __float2bfloat16(0.f);
    }
    __syncthreads();   // zero-init fully ordered before x0 seed
    if (tid < EPB)
        bcol[0][tid * BSTR + 51] = __float2bfloat16(x[(size_t)(e0 + tid) * SEQT]);
    const float bfc = b_fc[0];

    __syncthreads();

    for (int tc = 0; tc < NCH; ++tc) {
        const int t0 = tc * CH;
        for (int i2 = tid; i2 < (CH + 1) * EPB; i2 += NTH) {
            int ee = i2 / (CH + 1), tt = i2 % (CH + 1);
            int t = t0 + tt;
            x_lds[tt * XST + ee] = (t < SEQT) ? x[(size_t)(e0 + ee) * SEQT + t] : 0.f;
        }
        __syncthreads();

        for (int tt = 0; tt < CH; ++tt) {
            const int t  = t0 + tt;
            const int rp = t & 1, wp = rp ^ 1;

            // ONE B read per wave, shared by all of its tiles
            short8 B0 = *(const short8*)&bcol[rp][e * BSTR + g4 * 8];
            short8 B1 = *(const short8*)&bcol[rp][e * BSTR + 32 + g4 * 8];

#pragma unroll
            for (int ti = 0; ti < 4; ++ti) {
                if (ti >= NT) continue;     // wave-uniform, compile-time unrolled

                floatx4 acc = __builtin_amdgcn_mfma_f32_16x16x32_bf16(A0[ti], B0, bq[ti], 0, 0, 0);
                acc = __builtin_amdgcn_mfma_f32_16x16x32_bf16(A1[ti], B1, acc, 0, 0, 0);

                float Ei = __builtin_amdgcn_exp2f(acc[0]);
                float Ef = __builtin_amdgcn_exp2f(acc[1]);
                float Eg = __builtin_amdgcn_exp2f(acc[2]);
                float Eo = __builtin_amdgcn_exp2f(acc[3]);

                // merged-denominator cell update: ONE rcp for (i,f,g).
                //   c' = (c*P + K2N*(1-Eg)*F1) / (F1*P),  P=(1+Ei)(1+Eg), F1=1+Ef
                float P  = fmaf(Ei, Eg, (Ei + Eg) + 1.f);
                float F1 = 1.f + Ef;
                float R  = __builtin_amdgcn_rcpf(F1 * P);
                cs[ti] = fmaf(cs[ti], P, K2N * ((1.f - Eg) * F1)) * R;

                float Ec  = __builtin_amdgcn_exp2f(cs[ti]);
                float Roc = __builtin_amdgcn_rcpf(fmaf(Eo, Ec, (Eo + Ec) + 1.f));
                float h   = (1.f - Ec) * Roc;

                bcol[wp][e * BSTR + wr[ti]] = __float2bfloat16(real[ti] ? h : 0.f);
                if (ti == 3 && yln)
                    y_lds[tt * XST + e] = acc[0] + bfc;   // y[t-1], free
            }

            if (xsv) bcol[wp][e * BSTR + 51] =
                         __float2bfloat16(x_lds[(tt + 1) * XST + e]);

            __syncthreads();   // the ONE barrier per step
        }
        __syncthreads();

        // flush y[t0-1 .. t0+CH-2] (slot tt <-> t0+tt-1); skip t = -1
        for (int i2 = tid; i2 < CH * EPB; i2 += NTH) {
            int ee = i2 / CH, tt = i2 % CH;
            int t = t0 + tt - 1;
            if (t >= 0)
                out[(size_t)(e0 + ee) * SEQT + t] = y_lds[tt * XST + ee];
        }
        __syncthreads();
    }

    // epilogue: y[998] from one extra MFMA pass over h_998 (in bcol[1])
    if (w == 3) {
        short8 B0 = *(const short8*)&bcol[1][e * BSTR + g4 * 8];
        short8 B1 = *(const short8*)&bcol[1][e * BSTR + 32 + g4 * 8];
        floatx4 acc = __builtin_amdgcn_mfma_f32_16x16x32_bf16(A0[3], B0, bq[3], 0, 0, 0);
        acc = __builtin_amdgcn_mfma_f32_16x16x32_bf16(A1[3], B1, acc, 0, 0, 0);
        if (g4 == 3)
            out[(size_t)(e0 + e) * SEQT + (SEQT - 1)] = acc[0] + bfc;
    }
}

extern "C" void kernel_launch(void* const* d_in, const int* in_sizes, int n_in,
                              void* d_out, int out_size, void* d_ws, size_t ws_size,
                              hipStream_t stream) {
    const float* x    = (const float*)d_in[0];
    const float* W_ih = (const float*)d_in[1];
    const float* W_hh = (const float*)d_in[2];
    const float* b_ih = (const float*)d_in[3];
    const float* b_hh = (const float*)d_in[4];
    const float* W_fc = (const float*)d_in[5];
    const float* b_fc = (const float*)d_in[6];
    float* out = (float*)d_out;

    __hip_bfloat16* A_ext = (__hip_bfloat16*)d_ws;   // 208*64*2 = 26.6 KB

    prep_kernel<<<(MR * 64 + 255) / 256, 256, 0, stream>>>(W_hh, W_ih, W_fc, A_ext);
    lstm_mfma_kernel<<<4096 / EPB, NTH, 0, stream>>>(x, b_ih, b_hh,
                                                     b_fc, A_ext, out);
}

// Round 3
// 430.379 us; speedup vs baseline: 1.2952x; 1.2952x over previous
//
#include <hip/hip_runtime.h>
#include <hip/hip_bf16.h>

#define HID   51
#define MR    208          // 204 gate rows + y row (204) padded to 13 tiles of 16
#define SEQT  999
#define CH    111          // 999 = 9 * 111
#define NCH   9
#define EPB   16           // batch elements per block -> 256 blocks, full-width lanes
#define XST   17           // x/y LDS stride (EPB+1)
#define NTH   448          // 7 waves: waves 0-5 = 2 tiles each, wave 6 = tile 12 + service
#define BSTR  72           // bcol row stride in halves (144 B: 16B-aligned, free 2-way)

typedef __attribute__((ext_vector_type(8))) short  short8;   // 8 bf16 = 4 VGPRs
typedef __attribute__((ext_vector_type(4))) float  floatx4;

// A_ext[208][64] bf16, PRE-SCALED by -log2(e) (i,f,o) or -2*log2(e) (g).
// Row->unit map is PERMUTED so wave w's two tiles (2w, 2w+1) give lane group
// g4 the ADJACENT units 8w+2*g4 and 8w+2*g4+1 (packed dword h-write):
//   tile T<12, row group g4r, gate: unit u = 8*(T>>1) + 2*g4r + (T&1)
//   tile 12: g4r<3 -> unit 48+g4r;  g4r==3,gate==0 -> y row (W_fc, UNSCALED)
__global__ void prep_kernel(const float* __restrict__ W_hh,
                            const float* __restrict__ W_ih,
                            const float* __restrict__ W_fc,
                            __hip_bfloat16* __restrict__ A_ext)
{
    const float K1 = 1.442695040889f;
    int idx = blockIdx.x * blockDim.x + threadIdx.x;
    if (idx >= MR * 64) return;
    int r = idx >> 6, k = idx & 63;
    int T = r >> 4, r16 = r & 15, g4r = r16 >> 2, gate = r16 & 3;
    float v = 0.f;
    if (T < 12) {
        int u = ((T >> 1) << 3) + 2 * g4r + (T & 1);
        float s = (gate == 2) ? (-2.f * K1) : (-K1);
        if (k < HID)      v = s * W_hh[(gate * HID + u) * HID + k];
        else if (k == 51) v = s * W_ih[gate * HID + u];
    } else {                       // tile 12
        if (g4r < 3) {
            int u = 48 + g4r;
            float s = (gate == 2) ? (-2.f * K1) : (-K1);
            if (k < HID)      v = s * W_hh[(gate * HID + u) * HID + k];
            else if (k == 51) v = s * W_ih[gate * HID + u];
        } else if (gate == 0) {    // row 204: y row
            if (k < HID) v = W_fc[k];
        }
    }
    A_ext[idx] = __float2bfloat16(v);
}

__launch_bounds__(NTH)
__global__ void lstm_mfma_kernel(const float* __restrict__ x,
                                 const float* __restrict__ b_ih,
                                 const float* __restrict__ b_hh,
                                 const float* __restrict__ b_fc,
                                 const __hip_bfloat16* __restrict__ A_ext,
                                 float* __restrict__ out)
{
    __shared__ __hip_bfloat16 bcol[2][16 * BSTR];
    __shared__ float x_lds[(CH + 1) * XST];   // +1 lookahead for row-51 prewrite
    __shared__ float y_lds[CH * XST];         // slot tt holds y[t0 + tt - 1]

    const int tid  = threadIdx.x;
    const int w    = tid >> 6;    // 0..5 double-tile waves, 6 = tile-12 + service
    const int lane = tid & 63;
    const int e    = lane & 15;   // MFMA col — all 16 live
    const int g4   = lane >> 4;   // lane group
    const int e0   = blockIdx.x * EPB;
    const bool w6  = (w == 6);
    // wave 6 tile-12 units: 48+g4 for g4<3; g4==3 lanes own the y row (204)
    const int  uB6   = 48 + g4;
    const bool yln   = w6 && (g4 == 3);
    const bool xsv   = w6 && (g4 == 0);
    const int  wrow6 = (uB6 < HID) ? uB6 : 63;   // g4==3 -> dump row 63

    const float K1  = 1.442695040889f;
    const float K2N = -2.885390081777f;      // -2*log2(e)
    const floatx4 z4 = {0.f, 0.f, 0.f, 0.f};

    // waves 0-5: tiles 2w, 2w+1 -> ADJACENT units ua=8w+2g4, ub=ua+1
    short8  A0a = {0,0,0,0,0,0,0,0}, A1a = {0,0,0,0,0,0,0,0};
    short8  A0b = {0,0,0,0,0,0,0,0}, A1b = {0,0,0,0,0,0,0,0};
    floatx4 bqa = {0.f, 0.f, 0.f, 0.f}, bqb = {0.f, 0.f, 0.f, 0.f};
    float   csa = 0.f, csb = 0.f;            // cell states (pre-scaled)
    int ua = 0;

    if (!w6) {
        int Ta = 2 * w, Tb = 2 * w + 1;
        ua = 8 * w + 2 * g4;                 // even; ub = ua+1
        int ma = Ta * 16 + e, mb = Tb * 16 + e;
        A0a = *(const short8*)&A_ext[ma * 64 + g4 * 8];
        A1a = *(const short8*)&A_ext[ma * 64 + 32 + g4 * 8];
        A0b = *(const short8*)&A_ext[mb * 64 + g4 * 8];
        A1b = *(const short8*)&A_ext[mb * 64 + 32 + g4 * 8];
#pragma unroll
        for (int gg = 0; gg < 4; ++gg) {
            float s = (gg == 2) ? (-2.f * K1) : (-K1);
            bqa[gg] = s * (b_ih[gg * HID + ua]     + b_hh[gg * HID + ua]);
            bqb[gg] = s * (b_ih[gg * HID + ua + 1] + b_hh[gg * HID + ua + 1]);
        }
    } else {
        int m = 12 * 16 + e;
        A0a = *(const short8*)&A_ext[m * 64 + g4 * 8];
        A1a = *(const short8*)&A_ext[m * 64 + 32 + g4 * 8];
        if (uB6 < HID) {
#pragma unroll
            for (int gg = 0; gg < 4; ++gg) {
                float s = (gg == 2) ? (-2.f * K1) : (-K1);
                bqa[gg] = s * (b_ih[gg * HID + uB6] + b_hh[gg * HID + uB6]);
            }
        }
    }

    for (int i = tid; i < 16 * BSTR; i += NTH) {
        bcol[0][i] = __float2bfloat16(0.f);
        bcol[1][i] = __float2bfloat16(0.f);
    }
    __syncthreads();   // zero-init fully ordered before x0 seed
    if (tid < EPB)
        bcol[0][tid * BSTR + 51] = __float2bfloat16(x[(size_t)(e0 + tid) * SEQT]);
    // prologue x-stage for chunk 0 (t = tt, always < SEQT)
    for (int i2 = tid; i2 < (CH + 1) * EPB; i2 += NTH) {
        int ee = i2 / (CH + 1), tt = i2 % (CH + 1);
        x_lds[tt * XST + ee] = x[(size_t)(e0 + ee) * SEQT + tt];
    }
    const float bfc = b_fc[0];

    __syncthreads();

    for (int tc = 0; tc < NCH; ++tc) {
        const int t0 = tc * CH;

        // prefetch next chunk's x into registers (hides HBM latency under steps)
        float xpre[4];
        {
            const int t0n = t0 + CH;
#pragma unroll
            for (int q = 0; q < 4; ++q) {
                int i2 = tid + q * NTH;              // (CH+1)*EPB == 4*NTH exactly
                int ee = i2 / (CH + 1), tt = i2 - ee * (CH + 1);
                int t = t0n + tt;
                xpre[q] = (t < SEQT) ? x[(size_t)(e0 + ee) * SEQT + t] : 0.f;
            }
        }

        for (int tt = 0; tt < CH; ++tt) {
            const int t  = t0 + tt;
            const int rp = t & 1, wp = rp ^ 1;

            short8 B0 = *(const short8*)&bcol[rp][e * BSTR + g4 * 8];
            short8 B1 = *(const short8*)&bcol[rp][e * BSTR + 32 + g4 * 8];

            if (!w6) {
                // 4 INDEPENDENT MFMAs (split accumulators), combine via VALU
                floatx4 aa = __builtin_amdgcn_mfma_f32_16x16x32_bf16(A0a, B0, bqa, 0, 0, 0);
                floatx4 a2 = __builtin_amdgcn_mfma_f32_16x16x32_bf16(A1a, B1, z4,  0, 0, 0);
                floatx4 ab = __builtin_amdgcn_mfma_f32_16x16x32_bf16(A0b, B0, bqb, 0, 0, 0);
                floatx4 b2 = __builtin_amdgcn_mfma_f32_16x16x32_bf16(A1b, B1, z4,  0, 0, 0);

                float Eia = __builtin_amdgcn_exp2f(aa[0] + a2[0]);
                float Efa = __builtin_amdgcn_exp2f(aa[1] + a2[1]);
                float Ega = __builtin_amdgcn_exp2f(aa[2] + a2[2]);
                float Eoa = __builtin_amdgcn_exp2f(aa[3] + a2[3]);
                float Eib = __builtin_amdgcn_exp2f(ab[0] + b2[0]);
                float Efb = __builtin_amdgcn_exp2f(ab[1] + b2[1]);
                float Egb = __builtin_amdgcn_exp2f(ab[2] + b2[2]);
                float Eob = __builtin_amdgcn_exp2f(ab[3] + b2[3]);

                // merged-denominator cell update: ONE rcp for (i,f,g)
                //   c' = (c*P + K2N*(1-Eg)*F1) / (F1*P),  P=(1+Ei)(1+Eg), F1=1+Ef
                float Pa  = fmaf(Eia, Ega, (Eia + Ega) + 1.f);
                float Pb  = fmaf(Eib, Egb, (Eib + Egb) + 1.f);
                float F1a = 1.f + Efa;
                float F1b = 1.f + Efb;
                float Ra  = __builtin_amdgcn_rcpf(F1a * Pa);
                float Rb  = __builtin_amdgcn_rcpf(F1b * Pb);
                csa = fmaf(csa, Pa, K2N * ((1.f - Ega) * F1a)) * Ra;
                csb = fmaf(csb, Pb, K2N * ((1.f - Egb) * F1b)) * Rb;
                float Eca = __builtin_amdgcn_exp2f(csa);
                float Ecb = __builtin_amdgcn_exp2f(csb);
                float Roca = __builtin_amdgcn_rcpf(fmaf(Eoa, Eca, (Eoa + Eca) + 1.f));
                float Rocb = __builtin_amdgcn_rcpf(fmaf(Eob, Ecb, (Eob + Ecb) + 1.f));
                float ha = (1.f - Eca) * Roca;
                float hb = (1.f - Ecb) * Rocb;

                // pack two adjacent units into one aligned dword write
                unsigned hpk;
                asm("v_cvt_pk_bf16_f32 %0, %1, %2" : "=v"(hpk) : "v"(ha), "v"(hb));
                *(unsigned*)&bcol[wp][e * BSTR + ua] = hpk;
            } else {
                floatx4 acc = __builtin_amdgcn_mfma_f32_16x16x32_bf16(A0a, B0, bqa, 0, 0, 0);
                floatx4 ac2 = __builtin_amdgcn_mfma_f32_16x16x32_bf16(A1a, B1, z4,  0, 0, 0);

                float s0 = acc[0] + ac2[0];
                float Ei = __builtin_amdgcn_exp2f(s0);
                float Ef = __builtin_amdgcn_exp2f(acc[1] + ac2[1]);
                float Eg = __builtin_amdgcn_exp2f(acc[2] + ac2[2]);
                float Eo = __builtin_amdgcn_exp2f(acc[3] + ac2[3]);
                float P  = fmaf(Ei, Eg, (Ei + Eg) + 1.f);
                float F1 = 1.f + Ef;
                float R  = __builtin_amdgcn_rcpf(F1 * P);
                csa = fmaf(csa, P, K2N * ((1.f - Eg) * F1)) * R;
                float Ec  = __builtin_amdgcn_exp2f(csa);
                float Roc = __builtin_amdgcn_rcpf(fmaf(Eo, Ec, (Eo + Ec) + 1.f));
                float h   = (1.f - Ec) * Roc;

                bcol[wp][e * BSTR + wrow6] = __float2bfloat16((uB6 < HID) ? h : 0.f);
                if (yln) y_lds[tt * XST + e] = s0 + bfc;   // y[t-1], free
                if (xsv) bcol[wp][e * BSTR + 51] =
                             __float2bfloat16(x_lds[(tt + 1) * XST + e]);
            }

            __syncthreads();   // the ONE barrier per step
        }

        // flush y[t0-1 .. t0+CH-2] (slot tt <-> t0+tt-1); skip t = -1
        for (int i2 = tid; i2 < CH * EPB; i2 += NTH) {
            int ee = i2 / CH, tt = i2 % CH;
            int t = t0 + tt - 1;
            if (t >= 0)
                out[(size_t)(e0 + ee) * SEQT + t] = y_lds[tt * XST + ee];
        }
        // commit prefetched x for the next chunk
#pragma unroll
        for (int q = 0; q < 4; ++q) {
            int i2 = tid + q * NTH;
            int ee = i2 / (CH + 1), tt = i2 - ee * (CH + 1);
            x_lds[tt * XST + ee] = xpre[q];
        }
        __syncthreads();
    }

    // epilogue: y[998] from one extra MFMA pass over h_998 (in bcol[1])
    if (w6) {
        short8 B0 = *(const short8*)&bcol[1][e * BSTR + g4 * 8];
        short8 B1 = *(const short8*)&bcol[1][e * BSTR + 32 + g4 * 8];
        floatx4 acc = __builtin_amdgcn_mfma_f32_16x16x32_bf16(A0a, B0, bqa, 0, 0, 0);
        acc = __builtin_amdgcn_mfma_f32_16x16x32_bf16(A1a, B1, acc, 0, 0, 0);
        if (g4 == 3)
            out[(size_t)(e0 + e) * SEQT + (SEQT - 1)] = acc[0] + bfc;
    }
}

extern "C" void kernel_launch(void* const* d_in, const int* in_sizes, int n_in,
                              void* d_out, int out_size, void* d_ws, size_t ws_size,
                              hipStream_t stream) {
    const float* x    = (const float*)d_in[0];
    const float* W_ih = (const float*)d_in[1];
    const float* W_hh = (const float*)d_in[2];
    const float* b_ih = (const float*)d_in[3];
    const float* b_hh = (const float*)d_in[4];
    const float* W_fc = (const float*)d_in[5];
    const float* b_fc = (const float*)d_in[6];
    float* out = (float*)d_out;

    __hip_bfloat16* A_ext = (__hip_bfloat16*)d_ws;   // 208*64*2 = 26.6 KB

    prep_kernel<<<(MR * 64 + 255) / 256, 256, 0, stream>>>(W_hh, W_ih, W_fc, A_ext);
    lstm_mfma_kernel<<<4096 / EPB, NTH, 0, stream>>>(x, b_ih, b_hh,
                                                     b_fc, A_ext, out);
}